// Round 3
// baseline (69.584 us; speedup 1.0000x reference)
//
#include <hip/hip_runtime.h>
#include <math.h>

#define DIM 1280
#define NT 320              // threads per block: 320 * 4 cols = 1280 = DIM
#define ROWS_PER_BLOCK 32   // contiguous rows per block -> scalar time loads coalesce

typedef float f32x4 __attribute__((ext_vector_type(4)));  // native vector: OK for nontemporal builtins

// out[b][i] = i%2==0 ? sin(time[b]*rate(i)) : cos(time[b]*rate(i))
// rate(i) = 10000^(-(i//2)/640) = exp2(-(i//2) * log2(10000)/640)
__global__ __launch_bounds__(NT)
void time_emb_kernel(const float* __restrict__ time, float* __restrict__ out, int batch) {
    const int t = threadIdx.x;           // 0..319, owns columns 4t..4t+3
    const float L_over_640 = 13.287712379549449f / 640.0f;  // log2(10000)/640
    const float rate0 = exp2f(-(float)(2 * t)     * L_over_640);
    const float rate1 = exp2f(-(float)(2 * t + 1) * L_over_640);

    const int nblk_rows = (batch + ROWS_PER_BLOCK - 1) / ROWS_PER_BLOCK;
    for (int chunk = blockIdx.x; chunk < nblk_rows; chunk += gridDim.x) {
        const int row0 = chunk * ROWS_PER_BLOCK;

        if (row0 + ROWS_PER_BLOCK <= batch) {
            // fast path: full chunk, 4-row unroll with independent chains
            #pragma unroll
            for (int r = 0; r < ROWS_PER_BLOCK; r += 4) {
                const int b = row0 + r;
                // 4 consecutive scalar loads -> s_load_dwordx4, hoisted early
                const float tv0 = time[b + 0];
                const float tv1 = time[b + 1];
                const float tv2 = time[b + 2];
                const float tv3 = time[b + 3];

                float s, c;
                f32x4 v0, v1, v2, v3;
                __sincosf(tv0 * rate0, &s, &c); v0.x = s; v0.y = c;
                __sincosf(tv0 * rate1, &s, &c); v0.z = s; v0.w = c;
                __sincosf(tv1 * rate0, &s, &c); v1.x = s; v1.y = c;
                __sincosf(tv1 * rate1, &s, &c); v1.z = s; v1.w = c;
                __sincosf(tv2 * rate0, &s, &c); v2.x = s; v2.y = c;
                __sincosf(tv2 * rate1, &s, &c); v2.z = s; v2.w = c;
                __sincosf(tv3 * rate0, &s, &c); v3.x = s; v3.y = c;
                __sincosf(tv3 * rate1, &s, &c); v3.z = s; v3.w = c;

                f32x4* p0 = reinterpret_cast<f32x4*>(out + (size_t)(b + 0) * DIM + (t << 2));
                f32x4* p1 = reinterpret_cast<f32x4*>(out + (size_t)(b + 1) * DIM + (t << 2));
                f32x4* p2 = reinterpret_cast<f32x4*>(out + (size_t)(b + 2) * DIM + (t << 2));
                f32x4* p3 = reinterpret_cast<f32x4*>(out + (size_t)(b + 3) * DIM + (t << 2));
                __builtin_nontemporal_store(v0, p0);
                __builtin_nontemporal_store(v1, p1);
                __builtin_nontemporal_store(v2, p2);
                __builtin_nontemporal_store(v3, p3);
            }
        } else {
            // tail: per-row guard
            for (int r = 0; r < ROWS_PER_BLOCK; ++r) {
                const int b = row0 + r;
                if (b >= batch) break;
                const float tv = time[b];
                float s, c;
                f32x4 v;
                __sincosf(tv * rate0, &s, &c); v.x = s; v.y = c;
                __sincosf(tv * rate1, &s, &c); v.z = s; v.w = c;
                f32x4* p = reinterpret_cast<f32x4*>(out + (size_t)b * DIM + (t << 2));
                __builtin_nontemporal_store(v, p);
            }
        }
    }
}

extern "C" void kernel_launch(void* const* d_in, const int* in_sizes, int n_in,
                              void* d_out, int out_size, void* d_ws, size_t ws_size,
                              hipStream_t stream) {
    const float* time = (const float*)d_in[0];
    float* out = (float*)d_out;
    const int batch = in_sizes[0];       // 65536

    const int nchunks = (batch + ROWS_PER_BLOCK - 1) / ROWS_PER_BLOCK;  // 2048 at B=65536
    const int grid = nchunks < 2048 ? nchunks : 2048;
    time_emb_kernel<<<grid, NT, 0, stream>>>(time, out, batch);
}

// Round 4
// 65.001 us; speedup vs baseline: 1.0705x; 1.0705x over previous
//
#include <hip/hip_runtime.h>
#include <math.h>

#define DIM 1280
#define COL4 320            // DIM/4 float4-columns per row
#define NT 256
#define GRID 2560           // GRID*NT = 655360 = 320*2048 -> stride keeps col fixed, b += 2048

typedef float f32x4 __attribute__((ext_vector_type(4)));

// out[b][i] = i%2==0 ? sin(time[b]*rate(i)) : cos(time[b]*rate(i))
// rate(i) = 10000^(-(i//2)/640) = exp2(-(i//2) * log2(10000)/640)
__global__ __launch_bounds__(NT)
void time_emb_kernel(const float* __restrict__ time, f32x4* __restrict__ out4, int total4) {
    const int tid = blockIdx.x * NT + threadIdx.x;   // flat float4 index, iter 0
    const int col4 = tid % COL4;                     // fixed per thread across iters
    int b = tid / COL4;                              // row; advances by +2048 per iter

    const float L_over_640 = 13.287712379549449f / 640.0f;  // log2(10000)/640
    const float rate0 = exp2f(-(float)(2 * col4)     * L_over_640);
    const float rate1 = exp2f(-(float)(2 * col4 + 1) * L_over_640);

    #pragma unroll 4
    for (int idx = tid; idx < total4; idx += GRID * NT, b += 2048) {
        const float tv = time[b];                    // L1/L2-resident (256 KB total)
        float s0, c0, s1, c1;
        __sincosf(tv * rate0, &s0, &c0);
        __sincosf(tv * rate1, &s1, &c1);
        f32x4 v; v.x = s0; v.y = c0; v.z = s1; v.w = c1;
        out4[idx] = v;                               // coalesced dwordx4, uniform base + fixed lane offset
    }
}

extern "C" void kernel_launch(void* const* d_in, const int* in_sizes, int n_in,
                              void* d_out, int out_size, void* d_ws, size_t ws_size,
                              hipStream_t stream) {
    const float* time = (const float*)d_in[0];
    f32x4* out4 = (f32x4*)d_out;
    const int batch = in_sizes[0];                   // 65536
    const int total4 = batch * COL4;                 // 20,971,520 float4s

    time_emb_kernel<<<GRID, NT, 0, stream>>>(time, out4, total4);
}